// Round 2
// baseline (847.541 us; speedup 1.0000x reference)
//
#include <hip/hip_runtime.h>

#define K_CODES 1024
#define DIM     256
#define NB      16
#define NT      4096
#define NROWS   (NB * NT)                  // 65536
#define Q_SIZE  (NB * DIM * NT)            // 16777216
#define IDX_OFF ((size_t)Q_SIZE)
#define LOSS_OFF ((size_t)Q_SIZE + (size_t)NROWS)

#define TM 32          // rows per block
#define TN 64          // codes per tile
#define CCH 32         // channel chunk
#define A_STRIDE 40    // 160 B rows: 16B-aligned float4, conflict-free column reads
#define B_STRIDE 68    // 272 B rows: 16B-aligned float4 reads

// ---- exact replication of numpy pairwise_sum(a*a) for n=128 / n=256 --------
// numpy: r[0..7]=p[0..7]; for i=8..120 step 8: r[j]+=p[i+j];
//        res = ((r0+r1)+(r2+r3))+((r4+r5)+(r6+r7));   (ISA-independent C path)
template<int S>
__device__ __forceinline__ float np_pw128_sq(const float* __restrict__ a) {
#pragma clang fp contract(off)
    float r[8];
#pragma unroll
    for (int j = 0; j < 8; ++j) { float v = a[j * S]; r[j] = v * v; }
    for (int i = 8; i < 128; i += 8) {
#pragma unroll
        for (int j = 0; j < 8; ++j) { float v = a[(i + j) * S]; r[j] += v * v; }
    }
    return ((r[0] + r[1]) + (r[2] + r[3])) + ((r[4] + r[5]) + (r[6] + r[7]));
}

template<int S>
__device__ __forceinline__ float np_sum256_sq(const float* __restrict__ a) {
#pragma clang fp contract(off)
    float s0 = np_pw128_sq<S>(a);
    float s1 = np_pw128_sq<S>(a + 128 * S);
    return s0 + s1;   // numpy: pairwise(lo) + pairwise(hi)
}

// ---------------- K1: codebook norms (np-exact) + zero loss accumulator -----
__global__ __launch_bounds__(128) void k_norms(const float* __restrict__ cb,
                                               float* __restrict__ e2,
                                               double* __restrict__ loss_acc) {
    if (blockIdx.x == 0 && threadIdx.x == 0) *loss_acc = 0.0;
    int k = blockIdx.x * 128 + threadIdx.x;
    e2[k] = np_sum256_sq<1>(cb + (size_t)k * DIM);
}

// ---------------- K2: fused distance-GEMM + argmin + gather + loss ----------
__global__ __launch_bounds__(128) void k_main(const float* __restrict__ x,
                                              const float* __restrict__ cb,
                                              const float* __restrict__ e2,
                                              float* __restrict__ out,
                                              double* __restrict__ loss_acc) {
    __shared__ __align__(16) float Alds[DIM * A_STRIDE];   // 40960 B  x tile [c][t]
    __shared__ __align__(16) float Bs[CCH * B_STRIDE];     //  8704 B  cb chunk [c][k]
    __shared__ float As[TM];                               // np-exact ||f||^2 per row
    __shared__ int   bidx[TM];
    __shared__ float wred[2];

    const int tid = threadIdx.x;
    const int tx  = tid & 15;    // code dim
    const int ty  = tid >> 4;    // row dim (0..7)

    const int b  = blockIdx.x >> 7;          // 128 tiles per batch
    const int t0 = (blockIdx.x & 127) * TM;
    const float* xb = x + ((size_t)b * DIM) * NT + t0;

    // stage x tile: Alds[c][t], coalesced float4 along t
    {
        int u  = tid >> 3;          // 0..15
        int t4 = (tid & 7) * 4;     // 0..28
#pragma unroll
        for (int pass = 0; pass < 16; ++pass) {
            int c = pass * 16 + u;
            float4 v = *(const float4*)(xb + (size_t)c * NT + t4);
            *(float4*)(&Alds[c * A_STRIDE + t4]) = v;
        }
    }
    __syncthreads();

    // np-exact ||f||^2 per row (one thread per row; conflict-free column reads)
    if (tid < TM) As[tid] = np_sum256_sq<A_STRIDE>(&Alds[tid]);
    // (As is ordered before any fold read by the barriers inside the ch-loop)

    float bestv[4];
    int   besti[4];
#pragma unroll
    for (int i = 0; i < 4; ++i) { bestv[i] = 3.402823466e+38f; besti[i] = 0; }

    const int kk = tid >> 3;        // 0..15 : code lane for B staging
    const int cg = (tid & 7) * 4;   // 0..28 : channel group for B staging

    for (int kt = 0; kt < 16; ++kt) {
        const int k0 = kt * TN;
        const float* cbb = cb + (size_t)(k0 + kk) * DIM + cg;
        // prefetch code-norms for this tile (latency hidden behind MACs)
        float4 cn = *(const float4*)(e2 + k0 + tx * 4);
        // register prefetch of chunk 0 (4 codes x float4 per thread)
        float4 r0 = *(const float4*)(cbb);
        float4 r1 = *(const float4*)(cbb + 16 * DIM);
        float4 r2 = *(const float4*)(cbb + 32 * DIM);
        float4 r3 = *(const float4*)(cbb + 48 * DIM);

        float acc[4][4];
#pragma unroll
        for (int i = 0; i < 4; ++i)
#pragma unroll
            for (int j = 0; j < 4; ++j) acc[i][j] = 0.f;

        for (int ch = 0; ch < 8; ++ch) {
            __syncthreads();   // previous chunk fully consumed
            {   // transpose-write staged registers into Bs[c][k]
                float t0v[4] = { r0.x, r0.y, r0.z, r0.w };
                float t1v[4] = { r1.x, r1.y, r1.z, r1.w };
                float t2v[4] = { r2.x, r2.y, r2.z, r2.w };
                float t3v[4] = { r3.x, r3.y, r3.z, r3.w };
#pragma unroll
                for (int i = 0; i < 4; ++i) {
                    Bs[(cg + i) * B_STRIDE + kk]      = t0v[i];
                    Bs[(cg + i) * B_STRIDE + kk + 16] = t1v[i];
                    Bs[(cg + i) * B_STRIDE + kk + 32] = t2v[i];
                    Bs[(cg + i) * B_STRIDE + kk + 48] = t3v[i];
                }
            }
            if (ch < 7) {   // prefetch next chunk
                const float* p = cbb + (ch + 1) * CCH;
                r0 = *(const float4*)(p);
                r1 = *(const float4*)(p + 16 * DIM);
                r2 = *(const float4*)(p + 32 * DIM);
                r3 = *(const float4*)(p + 48 * DIM);
            }
            __syncthreads();

            const float* Ab = &Alds[(ch * CCH) * A_STRIDE + ty * 4];
            // strict sequential fma chain over c ascending: bit-matches BLAS
            // sgemm single-accumulator k-loop (x2 scaling commutes exactly)
#pragma unroll
            for (int c = 0; c < CCH; ++c) {
                float4 av = *(const float4*)(Ab + c * A_STRIDE);
                float4 bv = *(const float4*)(&Bs[c * B_STRIDE + tx * 4]);
                float a4[4] = { av.x, av.y, av.z, av.w };
                float b4[4] = { bv.x, bv.y, bv.z, bv.w };
#pragma unroll
                for (int i = 0; i < 4; ++i)
#pragma unroll
                    for (int j = 0; j < 4; ++j)
                        acc[i][j] = __builtin_fmaf(a4[i], b4[j], acc[i][j]);
            }
        }

        // fold: d = fl(fl(A - 2B) + C) exactly as numpy evaluates
        // (A - 2*acc: the x2 product is exact, so fma vs mul+sub give identical bits)
        {
            const float* cnp = (const float*)&cn;
            float Arow[4];
#pragma unroll
            for (int i = 0; i < 4; ++i) Arow[i] = As[ty * 4 + i];
#pragma unroll
            for (int j = 0; j < 4; ++j) {
                int kidx = k0 + tx * 4 + j;
                float kn = cnp[j];
#pragma unroll
                for (int i = 0; i < 4; ++i) {
                    float t1 = Arow[i] - 2.0f * acc[i][j];
                    float s  = t1 + kn;
                    if (s < bestv[i]) { bestv[i] = s; besti[i] = kidx; }  // strict <: first-min
                }
            }
        }
    }

    // lexicographic (value, index) min across the 16 tx lanes per row
#pragma unroll
    for (int i = 0; i < 4; ++i) {
        float v = bestv[i]; int idx = besti[i];
#pragma unroll
        for (int off = 1; off < 16; off <<= 1) {
            float ov = __shfl_xor(v, off);
            int   oi = __shfl_xor(idx, off);
            if (ov < v || (ov == v && oi < idx)) { v = ov; idx = oi; }
        }
        if (tx == 0) bidx[ty * 4 + i] = idx;
    }
    __syncthreads();

    // indices output (as float32 values)
    if (tid < TM) out[IDX_OFF + (size_t)blockIdx.x * TM + tid] = (float)bidx[tid];

    // fused epilogue: quantized gather + transpose write + loss partial
    float lsum = 0.f;
    {
        int tt = tid & 31;
        int cq = tid >> 5;   // 0..3
        int myidx = bidx[tt];
        const float* myrow = cb + (size_t)myidx * DIM;
        float* oq = out + ((size_t)b * DIM) * NT + t0 + tt;
#pragma unroll 4
        for (int cc = 0; cc < 64; ++cc) {
            int c = cc * 4 + cq;
            float q = myrow[c];                      // gather (L2-hot codebook)
            float d = q - Alds[c * A_STRIDE + tt];   // x tile still resident
            lsum += d * d;
            oq[(size_t)c * NT] = q;                  // coalesced along t
        }
    }
#pragma unroll
    for (int off = 32; off > 0; off >>= 1) lsum += __shfl_down(lsum, off);
    if ((tid & 63) == 0) wred[tid >> 6] = lsum;
    __syncthreads();
    if (tid == 0) atomicAdd(loss_acc, (double)wred[0] + (double)wred[1]);
}

// ---------------- K3: finalize scalar loss ----------------------------------
__global__ void k_final(const double* __restrict__ loss_acc, float* __restrict__ out) {
    // codebook_loss + 0.25*commit = 1.25 * mean((q - x)^2)
    out[LOSS_OFF] = (float)(*loss_acc * (1.25 / (double)Q_SIZE));
}

extern "C" void kernel_launch(void* const* d_in, const int* in_sizes, int n_in,
                              void* d_out, int out_size, void* d_ws, size_t ws_size,
                              hipStream_t stream) {
    const float* x  = (const float*)d_in[0];   // (16, 256, 4096) f32
    const float* cb = (const float*)d_in[1];   // (1024, 256) f32
    float* out = (float*)d_out;
    double* loss_acc = (double*)d_ws;
    float*  e2 = (float*)((char*)d_ws + 16);

    hipLaunchKernelGGL(k_norms, dim3(K_CODES / 128), dim3(128), 0, stream, cb, e2, loss_acc);
    hipLaunchKernelGGL(k_main,  dim3(NROWS / TM),    dim3(128), 0, stream, x, cb, e2, out, loss_acc);
    hipLaunchKernelGGL(k_final, dim3(1), dim3(1), 0, stream, loss_acc, out);
}

// Round 4
// 388.886 us; speedup vs baseline: 2.1794x; 2.1794x over previous
//
#include <hip/hip_runtime.h>

typedef unsigned int uint;
typedef unsigned short ushort_t;
typedef unsigned long long u64;
typedef __attribute__((ext_vector_type(8))) short bf16x8;
typedef __attribute__((ext_vector_type(4))) float f32x4;

#define K_CODES 1024
#define DIM     256
#define NB      16
#define NT      4096
#define NROWS   65536
#define Q_SIZE  16777216
#define IDX_OFF ((size_t)Q_SIZE)
#define LOSS_OFF ((size_t)(Q_SIZE + NROWS))

#define TM   32
#define AST  36          // Alds stride (words): 144 B rows, 16B-aligned
#define CAP  960
#define EPS  6e-3f

// fast-path ws layout: [0] loss double; [4096] e2 f32[1024]; [32768] cbf bf16 512 KB
#define WS_E2   4096
#define WS_CBF  32768
#define WS_REQ  (WS_CBF + K_CODES * DIM * 2)   // 557056

__device__ __forceinline__ ushort_t f2bf(float f) {
    uint u = __builtin_bit_cast(uint, f);
    return (ushort_t)((u + 0x7FFFu + ((u >> 16) & 1u)) >> 16);   // RNE
}

// ---- numpy pairwise_sum(a*a), n=256 (bit-exact, R2-verified) ---------------
template<int S>
__device__ __forceinline__ float np_pw128_sq(const float* __restrict__ a) {
#pragma clang fp contract(off)
    float r[8];
#pragma unroll
    for (int j = 0; j < 8; ++j) { float v = a[j * S]; r[j] = v * v; }
    for (int i = 8; i < 128; i += 8) {
#pragma unroll
        for (int j = 0; j < 8; ++j) { float v = a[(i + j) * S]; r[j] += v * v; }
    }
    return ((r[0] + r[1]) + (r[2] + r[3])) + ((r[4] + r[5]) + (r[6] + r[7]));
}
template<int S>
__device__ __forceinline__ float np_sum256_sq(const float* __restrict__ a) {
#pragma clang fp contract(off)
    float s0 = np_pw128_sq<S>(a);
    float s1 = np_pw128_sq<S>(a + 128 * S);
    return s0 + s1;
}

// ============================ FAST PATH (MFMA) ==============================

// K1: e2 norms + fragment-order bf16 codebook + loss=0
__global__ __launch_bounds__(256) void k_prep(const float* __restrict__ cb,
                                              float* __restrict__ e2,
                                              ushort_t* __restrict__ cbf,
                                              double* __restrict__ loss_acc) {
    int g = blockIdx.x;
    if (g < 128) {            // slot s = (tileN*8+kc)*64+lane; 16 B per slot
        int s    = g * 256 + threadIdx.x;          // 0..32767
        int lane = s & 63, kc = (s >> 6) & 7, tileN = s >> 9;
        int code = tileN * 16 + (lane & 15);
        int k0   = kc * 32 + (lane >> 4) * 8;
        const float* p = cb + (size_t)code * DIM + k0;
        union { ushort_t u[8]; bf16x8 v; } o;
#pragma unroll
        for (int j = 0; j < 8; ++j) o.u[j] = f2bf(p[j]);
        *(bf16x8*)(cbf + (size_t)s * 8) = o.v;
    } else if (g < 132) {     // np-exact code norms
        int k = (g - 128) * 256 + threadIdx.x;
        e2[k] = np_sum256_sq<1>(cb + (size_t)k * DIM);
    } else {
        if (threadIdx.x == 0) *loss_acc = 0.0;
    }
}

// K2: MFMA screen + candidate collect + exact np-chain rescore
__global__ __launch_bounds__(256, 2) void k_main_mfma(const float* __restrict__ x,
                                                      const float* __restrict__ cb,
                                                      const float* __restrict__ e2g,
                                                      const ushort_t* __restrict__ cbf,
                                                      float* __restrict__ out,
                                                      double* __restrict__ loss_acc) {
    __shared__ __align__(16) float    Alds[DIM * AST];       // 36864 B  x tile [c][t] fp32
    __shared__ __align__(16) ushort_t Bs[2 * 8 * 64 * 8];    // 16384 B  [half][kc][lane][8]
    __shared__ float e2s[K_CODES];                           //  4096 B
    __shared__ uint  cand[CAP];                              //  3840 B
    __shared__ float AsP[TM][8][2];                          //  2048 B
    __shared__ float As[TM];
    __shared__ u64   keys[TM];
    __shared__ int   cnt;
    __shared__ float wred[4];

    const int tid  = threadIdx.x;
    const int lane = tid & 63;
    const int wid  = tid >> 6;          // 0..3
    const int half = wid & 1;           // code half (tiles 0..31 / 32..63)
    const int r0   = (wid >> 1) * 16;   // row-group base
    const int col  = lane & 15;
    const int quad = lane >> 4;

    const int b  = blockIdx.x >> 7;
    const int t0 = (blockIdx.x & 127) * TM;
    const float* xb = x + (size_t)b * DIM * NT + t0;

    if (tid < TM) keys[tid] = ~0ull;
    if (tid == 0) cnt = 0;

    // stage x tile fp32 [c][t] (8x 128B segments per wave instruction)
    {
        int c0 = tid >> 3, t4 = (tid & 7) * 4;
#pragma unroll
        for (int pass = 0; pass < 8; ++pass) {
            int c = pass * 32 + c0;
            *(float4*)(&Alds[c * AST + t4]) = *(const float4*)(xb + (size_t)c * NT + t4);
        }
    }
    for (int i = tid; i < K_CODES; i += 256) e2s[i] = e2g[i];
    __syncthreads();

    // np row-norm partials: 8 threads per row, np accumulator j per 128-half
    {
#pragma clang fp contract(off)
        int rw = tid >> 3, j = tid & 7;
        float rlo = 0.f, rhi = 0.f;
        for (int m = 0; m < 16; ++m)  { float v = Alds[(j + 8 * m) * AST + rw];  rlo += v * v; }
        for (int m = 16; m < 32; ++m) { float v = Alds[(j + 8 * m) * AST + rw];  rhi += v * v; }
        AsP[rw][j][0] = rlo; AsP[rw][j][1] = rhi;
    }

    // A fragments: lane holds A[m = r0+col][k = kc*32 + quad*8 + j]
    bf16x8 afrag[8];
#pragma unroll
    for (int kc = 0; kc < 8; ++kc) {
        union { ushort_t u[8]; bf16x8 v; } tmp;
#pragma unroll
        for (int j = 0; j < 8; ++j)
            tmp.u[j] = f2bf(Alds[(kc * 32 + quad * 8 + j) * AST + r0 + col]);
        afrag[kc] = tmp.v;
    }

    // register-prefetch staging: chunk it = tiles {it, 32+it}, each 512 uint4 contiguous
    const uint4* cbfv = (const uint4*)cbf;
    uint4* Bsv = (uint4*)Bs;
    const int hh = tid & 127;
    const int hs = tid >> 7;            // which half this thread stages
    uint4 pre[4];
#pragma unroll
    for (int v = 0; v < 4; ++v)
        pre[v] = cbfv[(size_t)(hs * 32 + 0) * 512 + v * 128 + hh];

    __syncthreads();   // AsP complete (also: everyone past Alds-read of afrag)

    if (tid < TM) {    // np combine lo/hi then lo+hi (bit-exact np_sum256_sq)
        const float* p = &AsP[tid][0][0];
        float lo = ((p[0] + p[2]) + (p[4] + p[6])) + ((p[8] + p[10]) + (p[12] + p[14]));
        float hi = ((p[1] + p[3]) + (p[5] + p[7])) + ((p[9] + p[11]) + (p[13] + p[15]));
        As[tid] = lo + hi;
    }

    float rowmin[4] = {3.4e38f, 3.4e38f, 3.4e38f, 3.4e38f};
    float sb[16];

    for (int it = 0; it < 32; ++it) {
        // write staged regs -> Bs, prefetch next chunk
#pragma unroll
        for (int v = 0; v < 4; ++v)
            Bsv[hs * 512 + v * 128 + hh] = pre[v];
        if (it < 31) {
#pragma unroll
            for (int v = 0; v < 4; ++v)
                pre[v] = cbfv[(size_t)(hs * 32 + it + 1) * 512 + v * 128 + hh];
        }
        __syncthreads();   // Bs ready

        // 8 MFMA over kc for tile (half*32 + it)
        f32x4 acc = {0.f, 0.f, 0.f, 0.f};
        const ushort_t* bbase = Bs + (size_t)half * 8 * 64 * 8;
#pragma unroll
        for (int kc = 0; kc < 8; ++kc) {
            bf16x8 bf = *(const bf16x8*)(bbase + (size_t)(kc * 64 + lane) * 8);
            acc = __builtin_amdgcn_mfma_f32_16x16x32_bf16(afrag[kc], bf, acc, 0, 0, 0);
        }
        int tileIdx = half * 32 + it;
        float e2v = e2s[tileIdx * 16 + col];
#pragma unroll
        for (int r = 0; r < 4; ++r) sb[(it & 3) * 4 + r] = e2v - 2.0f * acc[r];

        if ((it & 3) == 3) {   // checkpoint: row-min over 64 codes + candidate collect
            float bm[4];
#pragma unroll
            for (int r = 0; r < 4; ++r)
                bm[r] = fminf(fminf(sb[r], sb[4 + r]), fminf(sb[8 + r], sb[12 + r]));
#pragma unroll
            for (int mask = 1; mask < 16; mask <<= 1)
#pragma unroll
                for (int r = 0; r < 4; ++r) bm[r] = fminf(bm[r], __shfl_xor(bm[r], mask, 64));
#pragma unroll
            for (int r = 0; r < 4; ++r) rowmin[r] = fminf(rowmin[r], bm[r]);
#pragma unroll
            for (int tb = 0; tb < 4; ++tb)
#pragma unroll
                for (int r = 0; r < 4; ++r)
                    if (sb[tb * 4 + r] <= rowmin[r] + EPS) {
                        int code = (half * 32 + (it - 3 + tb)) * 16 + col;
                        int rowL = r0 + quad * 4 + r;
                        int pos  = atomicAdd(&cnt, 1);
                        if (pos < CAP) cand[pos] = ((uint)rowL << 10) | (uint)code;
                    }
        }
        __syncthreads();       // Bs consumed by all waves
    }

    // exact np-chain rescore (identical arithmetic to R2-proven kernel)
    {
        int n = cnt;
        bool over = (n > CAP);
        int total = over ? (TM * K_CODES) : n;
        for (int i = tid; i < total; i += 256) {
            uint pk   = over ? (uint)i : cand[i];
            int row   = pk >> 10;
            int code  = pk & 1023;
            const float* crow = cb + (size_t)code * DIM;
            float acc = 0.f;
            for (int c = 0; c < DIM; ++c)
                acc = __builtin_fmaf(Alds[c * AST + row], crow[c], acc);
            float t1 = As[row] - 2.0f * acc;     // fl(A-2B): 2*acc exact
            float d  = t1 + e2s[code];           // fl(+C)
            uint ub  = __builtin_bit_cast(uint, d);
            ub = (ub >> 31) ? ~ub : (ub | 0x80000000u);   // sortable float key
            atomicMin(&keys[row], ((u64)ub << 32) | (u64)(uint)code);
        }
    }
    __syncthreads();

    if (tid < TM) out[IDX_OFF + (size_t)blockIdx.x * TM + tid] =
        (float)(int)(keys[tid] & 1023u);

    // epilogue: gather q, transposed coalesced write, loss partial
    float lsum = 0.f;
    {
        int tt = tid & 31;
        int cq = tid >> 5;     // 0..7
        int myidx = (int)(keys[tt] & 1023u);
        const float* myrow = cb + (size_t)myidx * DIM;
        float* oq = out + (size_t)b * DIM * NT + t0 + tt;
#pragma unroll 4
        for (int cc = 0; cc < 32; ++cc) {
            int c = cc * 8 + cq;
            float q = myrow[c];
            float dd = q - Alds[c * AST + tt];
            lsum += dd * dd;
            oq[(size_t)c * NT] = q;
        }
    }
#pragma unroll
    for (int off = 32; off > 0; off >>= 1) lsum += __shfl_down(lsum, off);
    if (lane == 0) wred[wid] = lsum;
    __syncthreads();
    if (tid == 0)
        atomicAdd(loss_acc, (double)wred[0] + (double)wred[1] + (double)wred[2] + (double)wred[3]);
}

// ======================= FALLBACK PATH (R2, proven) =========================

#define F_A_STRIDE 40
#define F_B_STRIDE 68
#define F_TN 64
#define F_CCH 32

__global__ __launch_bounds__(128) void k_norms_fb(const float* __restrict__ cb,
                                                  float* __restrict__ e2,
                                                  double* __restrict__ loss_acc) {
    if (blockIdx.x == 0 && threadIdx.x == 0) *loss_acc = 0.0;
    int k = blockIdx.x * 128 + threadIdx.x;
    e2[k] = np_sum256_sq<1>(cb + (size_t)k * DIM);
}

__global__ __launch_bounds__(128) void k_main_fp32(const float* __restrict__ x,
                                                   const float* __restrict__ cb,
                                                   const float* __restrict__ e2,
                                                   float* __restrict__ out,
                                                   double* __restrict__ loss_acc) {
    __shared__ __align__(16) float Alds[DIM * F_A_STRIDE];
    __shared__ __align__(16) float Bst[F_CCH * F_B_STRIDE];
    __shared__ float As[TM];
    __shared__ int   bidx[TM];
    __shared__ float wred[2];

    const int tid = threadIdx.x;
    const int tx  = tid & 15;
    const int ty  = tid >> 4;

    const int b  = blockIdx.x >> 7;
    const int t0 = (blockIdx.x & 127) * TM;
    const float* xb = x + ((size_t)b * DIM) * NT + t0;

    {
        int u  = tid >> 3;
        int t4 = (tid & 7) * 4;
#pragma unroll
        for (int pass = 0; pass < 16; ++pass) {
            int c = pass * 16 + u;
            float4 v = *(const float4*)(xb + (size_t)c * NT + t4);
            *(float4*)(&Alds[c * F_A_STRIDE + t4]) = v;
        }
    }
    __syncthreads();
    if (tid < TM) As[tid] = np_sum256_sq<F_A_STRIDE>(&Alds[tid]);

    float bestv[4];
    int   besti[4];
#pragma unroll
    for (int i = 0; i < 4; ++i) { bestv[i] = 3.402823466e+38f; besti[i] = 0; }

    const int kk = tid >> 3;
    const int cg = (tid & 7) * 4;

    for (int kt = 0; kt < 16; ++kt) {
        const int k0 = kt * F_TN;
        const float* cbb = cb + (size_t)(k0 + kk) * DIM + cg;
        float4 cn = *(const float4*)(e2 + k0 + tx * 4);
        float4 q0 = *(const float4*)(cbb);
        float4 q1 = *(const float4*)(cbb + 16 * DIM);
        float4 q2 = *(const float4*)(cbb + 32 * DIM);
        float4 q3 = *(const float4*)(cbb + 48 * DIM);

        float acc[4][4];
#pragma unroll
        for (int i = 0; i < 4; ++i)
#pragma unroll
            for (int j = 0; j < 4; ++j) acc[i][j] = 0.f;

        for (int ch = 0; ch < 8; ++ch) {
            __syncthreads();
            {
                float t0v[4] = { q0.x, q0.y, q0.z, q0.w };
                float t1v[4] = { q1.x, q1.y, q1.z, q1.w };
                float t2v[4] = { q2.x, q2.y, q2.z, q2.w };
                float t3v[4] = { q3.x, q3.y, q3.z, q3.w };
#pragma unroll
                for (int i = 0; i < 4; ++i) {
                    Bst[(cg + i) * F_B_STRIDE + kk]      = t0v[i];
                    Bst[(cg + i) * F_B_STRIDE + kk + 16] = t1v[i];
                    Bst[(cg + i) * F_B_STRIDE + kk + 32] = t2v[i];
                    Bst[(cg + i) * F_B_STRIDE + kk + 48] = t3v[i];
                }
            }
            if (ch < 7) {
                const float* p = cbb + (ch + 1) * F_CCH;
                q0 = *(const float4*)(p);
                q1 = *(const float4*)(p + 16 * DIM);
                q2 = *(const float4*)(p + 32 * DIM);
                q3 = *(const float4*)(p + 48 * DIM);
            }
            __syncthreads();

            const float* Ab = &Alds[(ch * F_CCH) * F_A_STRIDE + ty * 4];
#pragma unroll
            for (int c = 0; c < F_CCH; ++c) {
                float4 av = *(const float4*)(Ab + c * F_A_STRIDE);
                float4 bv = *(const float4*)(&Bst[c * F_B_STRIDE + tx * 4]);
                float a4[4] = { av.x, av.y, av.z, av.w };
                float b4[4] = { bv.x, bv.y, bv.z, bv.w };
#pragma unroll
                for (int i = 0; i < 4; ++i)
#pragma unroll
                    for (int j = 0; j < 4; ++j)
                        acc[i][j] = __builtin_fmaf(a4[i], b4[j], acc[i][j]);
            }
        }

        {
            const float* cnp = (const float*)&cn;
            float Arow[4];
#pragma unroll
            for (int i = 0; i < 4; ++i) Arow[i] = As[ty * 4 + i];
#pragma unroll
            for (int j = 0; j < 4; ++j) {
                int kidx = k0 + tx * 4 + j;
                float kn = cnp[j];
#pragma unroll
                for (int i = 0; i < 4; ++i) {
                    float t1 = Arow[i] - 2.0f * acc[i][j];
                    float s  = t1 + kn;
                    if (s < bestv[i]) { bestv[i] = s; besti[i] = kidx; }
                }
            }
        }
    }

#pragma unroll
    for (int i = 0; i < 4; ++i) {
        float v = bestv[i]; int idx = besti[i];
#pragma unroll
        for (int off = 1; off < 16; off <<= 1) {
            float ov = __shfl_xor(v, off);
            int   oi = __shfl_xor(idx, off);
            if (ov < v || (ov == v && oi < idx)) { v = ov; idx = oi; }
        }
        if (tx == 0) bidx[ty * 4 + i] = idx;
    }
    __syncthreads();

    if (tid < TM) out[IDX_OFF + (size_t)blockIdx.x * TM + tid] = (float)bidx[tid];

    float lsum = 0.f;
    {
        int tt = tid & 31;
        int cq = tid >> 5;
        int myidx = bidx[tt];
        const float* myrow = cb + (size_t)myidx * DIM;
        float* oq = out + ((size_t)b * DIM) * NT + t0 + tt;
#pragma unroll 4
        for (int cc = 0; cc < 64; ++cc) {
            int c = cc * 4 + cq;
            float q = myrow[c];
            float d = q - Alds[c * F_A_STRIDE + tt];
            lsum += d * d;
            oq[(size_t)c * NT] = q;
        }
    }
#pragma unroll
    for (int off = 32; off > 0; off >>= 1) lsum += __shfl_down(lsum, off);
    if ((tid & 63) == 0) wred[tid >> 6] = lsum;
    __syncthreads();
    if (tid == 0) atomicAdd(loss_acc, (double)wred[0] + (double)wred[1]);
}

// ---------------- finalize scalar loss --------------------------------------
__global__ void k_final(const double* __restrict__ loss_acc, float* __restrict__ out) {
    out[LOSS_OFF] = (float)(*loss_acc * (1.25 / (double)Q_SIZE));
}

extern "C" void kernel_launch(void* const* d_in, const int* in_sizes, int n_in,
                              void* d_out, int out_size, void* d_ws, size_t ws_size,
                              hipStream_t stream) {
    const float* x  = (const float*)d_in[0];
    const float* cb = (const float*)d_in[1];
    float* out = (float*)d_out;
    double* loss_acc = (double*)d_ws;

    if (ws_size >= (size_t)WS_REQ) {
        float*    e2  = (float*)((char*)d_ws + WS_E2);
        ushort_t* cbf = (ushort_t*)((char*)d_ws + WS_CBF);
        hipLaunchKernelGGL(k_prep, dim3(133), dim3(256), 0, stream, cb, e2, cbf, loss_acc);
        hipLaunchKernelGGL(k_main_mfma, dim3(NROWS / TM), dim3(256), 0, stream,
                           x, cb, e2, cbf, out, loss_acc);
    } else {
        float* e2 = (float*)((char*)d_ws + 16);
        hipLaunchKernelGGL(k_norms_fb, dim3(K_CODES / 128), dim3(128), 0, stream,
                           cb, e2, loss_acc);
        hipLaunchKernelGGL(k_main_fp32, dim3(NROWS / TM), dim3(128), 0, stream,
                           x, cb, e2, out, loss_acc);
    }
    hipLaunchKernelGGL(k_final, dim3(1), dim3(1), 0, stream, loss_acc, out);
}

// Round 5
// 321.546 us; speedup vs baseline: 2.6358x; 1.2094x over previous
//
#include <hip/hip_runtime.h>

typedef unsigned int uint;
typedef unsigned short ushort_t;
typedef unsigned long long u64;
typedef __attribute__((ext_vector_type(8))) short bf16x8;
typedef __attribute__((ext_vector_type(4))) float f32x4;

#define K_CODES 1024
#define DIM     256
#define NB      16
#define NT      4096
#define NROWS   65536
#define Q_SIZE  16777216
#define IDX_OFF ((size_t)Q_SIZE)
#define LOSS_OFF ((size_t)(Q_SIZE + NROWS))

#define TM   32
#define AST  36          // Alds stride (words): 144 B rows, 16B-aligned
#define CAP  960
#define EPS  6e-3f

// fast-path ws layout: [0] loss double; [4096] e2 f32[1024]; [32768] cbf bf16 512 KB
#define WS_E2   4096
#define WS_CBF  32768
#define WS_REQ  (WS_CBF + K_CODES * DIM * 2)   // 557056

__device__ __forceinline__ ushort_t f2bf(float f) {
    uint u = __builtin_bit_cast(uint, f);
    return (ushort_t)((u + 0x7FFFu + ((u >> 16) & 1u)) >> 16);   // RNE
}

// ---- numpy pairwise_sum(a*a), n=256 (bit-exact, R2-verified) ---------------
template<int S>
__device__ __forceinline__ float np_pw128_sq(const float* __restrict__ a) {
#pragma clang fp contract(off)
    float r[8];
#pragma unroll
    for (int j = 0; j < 8; ++j) { float v = a[j * S]; r[j] = v * v; }
    for (int i = 8; i < 128; i += 8) {
#pragma unroll
        for (int j = 0; j < 8; ++j) { float v = a[(i + j) * S]; r[j] += v * v; }
    }
    return ((r[0] + r[1]) + (r[2] + r[3])) + ((r[4] + r[5]) + (r[6] + r[7]));
}
template<int S>
__device__ __forceinline__ float np_sum256_sq(const float* __restrict__ a) {
#pragma clang fp contract(off)
    float s0 = np_pw128_sq<S>(a);
    float s1 = np_pw128_sq<S>(a + 128 * S);
    return s0 + s1;
}

// ============================ FAST PATH (MFMA) ==============================

// K1: e2 norms + fragment-order bf16 codebook + loss=0
__global__ __launch_bounds__(256) void k_prep(const float* __restrict__ cb,
                                              float* __restrict__ e2,
                                              ushort_t* __restrict__ cbf,
                                              double* __restrict__ loss_acc) {
    int g = blockIdx.x;
    if (g < 128) {            // slot s = (tileN*8+kc)*64+lane; 16 B per slot
        int s    = g * 256 + threadIdx.x;          // 0..32767
        int lane = s & 63, kc = (s >> 6) & 7, tileN = s >> 9;
        int code = tileN * 16 + (lane & 15);
        int k0   = kc * 32 + (lane >> 4) * 8;
        const float* p = cb + (size_t)code * DIM + k0;
        union { ushort_t u[8]; bf16x8 v; } o;
#pragma unroll
        for (int j = 0; j < 8; ++j) o.u[j] = f2bf(p[j]);
        *(bf16x8*)(cbf + (size_t)s * 8) = o.v;
    } else if (g < 132) {     // np-exact code norms
        int k = (g - 128) * 256 + threadIdx.x;
        e2[k] = np_sum256_sq<1>(cb + (size_t)k * DIM);
    } else {
        if (threadIdx.x == 0) *loss_acc = 0.0;
    }
}

// K2: barrier-free MFMA screen (B direct global->VGPR) + exact np rescore
__global__ __launch_bounds__(256, 3) void k_main_mfma(const float* __restrict__ x,
                                                      const float* __restrict__ cb,
                                                      const float* __restrict__ e2g,
                                                      const ushort_t* __restrict__ cbf,
                                                      float* __restrict__ out,
                                                      double* __restrict__ loss_acc) {
    __shared__ __align__(16) float Alds[DIM * AST];          // 36864 B  x tile [c][t] fp32
    __shared__ float e2s[K_CODES];                           //  4096 B
    __shared__ uint  cand[CAP];                              //  3840 B
    __shared__ float AsP[TM][8][2];                          //  2048 B
    __shared__ float As[TM];
    __shared__ u64   keys[TM];
    __shared__ int   cnt;
    __shared__ float wred[4];

    const int tid  = threadIdx.x;
    const int lane = tid & 63;
    const int wid  = tid >> 6;          // 0..3
    const int half = wid & 1;           // code half (tiles 0..31 / 32..63)
    const int r0   = (wid >> 1) * 16;   // row-group base
    const int col  = lane & 15;
    const int quad = lane >> 4;

    const int b  = blockIdx.x >> 7;
    const int t0 = (blockIdx.x & 127) * TM;
    const float* xb = x + (size_t)b * DIM * NT + t0;

    if (tid < TM) keys[tid] = ~0ull;
    if (tid == 0) cnt = 0;

    // stage x tile fp32 [c][t]
    {
        int c0 = tid >> 3, t4 = (tid & 7) * 4;
#pragma unroll
        for (int pass = 0; pass < 8; ++pass) {
            int c = pass * 32 + c0;
            *(float4*)(&Alds[c * AST + t4]) = *(const float4*)(xb + (size_t)c * NT + t4);
        }
    }
    for (int i = tid; i < K_CODES; i += 256) e2s[i] = e2g[i];
    __syncthreads();

    // np row-norm partials: 8 threads per row, np accumulator j per 128-half
    {
#pragma clang fp contract(off)
        int rw = tid >> 3, j = tid & 7;
        float rlo = 0.f, rhi = 0.f;
        for (int m = 0; m < 16; ++m)  { float v = Alds[(j + 8 * m) * AST + rw];  rlo += v * v; }
        for (int m = 16; m < 32; ++m) { float v = Alds[(j + 8 * m) * AST + rw];  rhi += v * v; }
        AsP[rw][j][0] = rlo; AsP[rw][j][1] = rhi;
    }

    // A fragments: lane holds A[m = r0+col][k = kc*32 + quad*8 + j]
    bf16x8 afrag[8];
#pragma unroll
    for (int kc = 0; kc < 8; ++kc) {
        union { ushort_t u[8]; bf16x8 v; } tmp;
#pragma unroll
        for (int j = 0; j < 8; ++j)
            tmp.u[j] = f2bf(Alds[(kc * 32 + quad * 8 + j) * AST + r0 + col]);
        afrag[kc] = tmp.v;
    }

    __syncthreads();   // AsP complete

    if (tid < TM) {    // np combine lo/hi then lo+hi (bit-exact np_sum256_sq)
        const float* p = &AsP[tid][0][0];
        float lo = ((p[0] + p[2]) + (p[4] + p[6])) + ((p[8] + p[10]) + (p[12] + p[14]));
        float hi = ((p[1] + p[3]) + (p[5] + p[7])) + ((p[9] + p[11]) + (p[13] + p[15]));
        As[tid] = lo + hi;
    }

    // ---- barrier-free K-loop: B fragments straight from global (L2-hot) ----
    float rowmin[4] = {3.4e38f, 3.4e38f, 3.4e38f, 3.4e38f};
    float sb[16];
    const ushort_t* cbh = cbf + (size_t)(half * 32) * 8 * 64 * 8;  // this half's tiles

#pragma unroll
    for (int it = 0; it < 32; ++it) {
        bf16x8 bf[8];
#pragma unroll
        for (int kc = 0; kc < 8; ++kc)
            bf[kc] = *(const bf16x8*)(cbh + (size_t)((it * 8 + kc) * 64 + lane) * 8);
        f32x4 acc = {0.f, 0.f, 0.f, 0.f};
#pragma unroll
        for (int kc = 0; kc < 8; ++kc)
            acc = __builtin_amdgcn_mfma_f32_16x16x32_bf16(afrag[kc], bf[kc], acc, 0, 0, 0);

        int tileIdx = half * 32 + it;
        float e2v = e2s[tileIdx * 16 + col];
#pragma unroll
        for (int r = 0; r < 4; ++r) sb[(it & 3) * 4 + r] = e2v - 2.0f * acc[r];

        if ((it & 3) == 3) {   // checkpoint: row-min over last 64 codes + collect
            float bm[4];
#pragma unroll
            for (int r = 0; r < 4; ++r)
                bm[r] = fminf(fminf(sb[r], sb[4 + r]), fminf(sb[8 + r], sb[12 + r]));
#pragma unroll
            for (int mask = 1; mask < 16; mask <<= 1)
#pragma unroll
                for (int r = 0; r < 4; ++r) bm[r] = fminf(bm[r], __shfl_xor(bm[r], mask, 64));
#pragma unroll
            for (int r = 0; r < 4; ++r) rowmin[r] = fminf(rowmin[r], bm[r]);
#pragma unroll
            for (int tb = 0; tb < 4; ++tb)
#pragma unroll
                for (int r = 0; r < 4; ++r)
                    if (sb[tb * 4 + r] <= rowmin[r] + EPS) {
                        int code = (half * 32 + (it - 3 + tb)) * 16 + col;
                        int rowL = r0 + quad * 4 + r;
                        int pos  = atomicAdd(&cnt, 1);
                        if (pos < CAP) cand[pos] = ((uint)rowL << 10) | (uint)code;
                    }
        }
    }
    __syncthreads();   // cand/cnt/As all ready

    // exact np-chain rescore (identical arithmetic to R2-proven kernel)
    {
        int n = cnt;
        bool over = (n > CAP);
        int total = over ? (TM * K_CODES) : n;
        for (int i = tid; i < total; i += 256) {
            uint pk   = over ? (uint)i : cand[i];
            int row   = pk >> 10;
            int code  = pk & 1023;
            const float* crow = cb + (size_t)code * DIM;
            float acc = 0.f;
#pragma unroll 8
            for (int c = 0; c < DIM; ++c)
                acc = __builtin_fmaf(Alds[c * AST + row], crow[c], acc);
            float t1 = As[row] - 2.0f * acc;     // fl(A-2B): 2*acc exact
            float d  = t1 + e2s[code];           // fl(+C)
            uint ub  = __builtin_bit_cast(uint, d);
            ub = (ub >> 31) ? ~ub : (ub | 0x80000000u);   // sortable float key
            atomicMin(&keys[row], ((u64)ub << 32) | (u64)(uint)code);
        }
    }
    __syncthreads();

    if (tid < TM) out[IDX_OFF + (size_t)blockIdx.x * TM + tid] =
        (float)(int)(keys[tid] & 1023u);

    // epilogue: gather q, transposed coalesced write, loss partial
    float lsum = 0.f;
    {
        int tt = tid & 31;
        int cq = tid >> 5;     // 0..7
        int myidx = (int)(keys[tt] & 1023u);
        const float* myrow = cb + (size_t)myidx * DIM;
        float* oq = out + (size_t)b * DIM * NT + t0 + tt;
#pragma unroll 4
        for (int cc = 0; cc < 32; ++cc) {
            int c = cc * 8 + cq;
            float q = myrow[c];
            float dd = q - Alds[c * AST + tt];
            lsum += dd * dd;
            oq[(size_t)c * NT] = q;
        }
    }
#pragma unroll
    for (int off = 32; off > 0; off >>= 1) lsum += __shfl_down(lsum, off);
    if (lane == 0) wred[wid] = lsum;
    __syncthreads();
    if (tid == 0)
        atomicAdd(loss_acc, (double)wred[0] + (double)wred[1] + (double)wred[2] + (double)wred[3]);
}

// ======================= FALLBACK PATH (R2, proven) =========================

#define F_A_STRIDE 40
#define F_B_STRIDE 68
#define F_TN 64
#define F_CCH 32

__global__ __launch_bounds__(128) void k_norms_fb(const float* __restrict__ cb,
                                                  float* __restrict__ e2,
                                                  double* __restrict__ loss_acc) {
    if (blockIdx.x == 0 && threadIdx.x == 0) *loss_acc = 0.0;
    int k = blockIdx.x * 128 + threadIdx.x;
    e2[k] = np_sum256_sq<1>(cb + (size_t)k * DIM);
}

__global__ __launch_bounds__(128) void k_main_fp32(const float* __restrict__ x,
                                                   const float* __restrict__ cb,
                                                   const float* __restrict__ e2,
                                                   float* __restrict__ out,
                                                   double* __restrict__ loss_acc) {
    __shared__ __align__(16) float Alds[DIM * F_A_STRIDE];
    __shared__ __align__(16) float Bst[F_CCH * F_B_STRIDE];
    __shared__ float As[TM];
    __shared__ int   bidx[TM];
    __shared__ float wred[2];

    const int tid = threadIdx.x;
    const int tx  = tid & 15;
    const int ty  = tid >> 4;

    const int b  = blockIdx.x >> 7;
    const int t0 = (blockIdx.x & 127) * TM;
    const float* xb = x + ((size_t)b * DIM) * NT + t0;

    {
        int u  = tid >> 3;
        int t4 = (tid & 7) * 4;
#pragma unroll
        for (int pass = 0; pass < 16; ++pass) {
            int c = pass * 16 + u;
            float4 v = *(const float4*)(xb + (size_t)c * NT + t4);
            *(float4*)(&Alds[c * F_A_STRIDE + t4]) = v;
        }
    }
    __syncthreads();
    if (tid < TM) As[tid] = np_sum256_sq<F_A_STRIDE>(&Alds[tid]);

    float bestv[4];
    int   besti[4];
#pragma unroll
    for (int i = 0; i < 4; ++i) { bestv[i] = 3.402823466e+38f; besti[i] = 0; }

    const int kk = tid >> 3;
    const int cg = (tid & 7) * 4;

    for (int kt = 0; kt < 16; ++kt) {
        const int k0 = kt * F_TN;
        const float* cbb = cb + (size_t)(k0 + kk) * DIM + cg;
        float4 cn = *(const float4*)(e2 + k0 + tx * 4);
        float4 q0 = *(const float4*)(cbb);
        float4 q1 = *(const float4*)(cbb + 16 * DIM);
        float4 q2 = *(const float4*)(cbb + 32 * DIM);
        float4 q3 = *(const float4*)(cbb + 48 * DIM);

        float acc[4][4];
#pragma unroll
        for (int i = 0; i < 4; ++i)
#pragma unroll
            for (int j = 0; j < 4; ++j) acc[i][j] = 0.f;

        for (int ch = 0; ch < 8; ++ch) {
            __syncthreads();
            {
                float t0v[4] = { q0.x, q0.y, q0.z, q0.w };
                float t1v[4] = { q1.x, q1.y, q1.z, q1.w };
                float t2v[4] = { q2.x, q2.y, q2.z, q2.w };
                float t3v[4] = { q3.x, q3.y, q3.z, q3.w };
#pragma unroll
                for (int i = 0; i < 4; ++i) {
                    Bst[(cg + i) * F_B_STRIDE + kk]      = t0v[i];
                    Bst[(cg + i) * F_B_STRIDE + kk + 16] = t1v[i];
                    Bst[(cg + i) * F_B_STRIDE + kk + 32] = t2v[i];
                    Bst[(cg + i) * F_B_STRIDE + kk + 48] = t3v[i];
                }
            }
            if (ch < 7) {
                const float* p = cbb + (ch + 1) * F_CCH;
                q0 = *(const float4*)(p);
                q1 = *(const float4*)(p + 16 * DIM);
                q2 = *(const float4*)(p + 32 * DIM);
                q3 = *(const float4*)(p + 48 * DIM);
            }
            __syncthreads();

            const float* Ab = &Alds[(ch * F_CCH) * F_A_STRIDE + ty * 4];
#pragma unroll
            for (int c = 0; c < F_CCH; ++c) {
                float4 av = *(const float4*)(Ab + c * F_A_STRIDE);
                float4 bv = *(const float4*)(&Bst[c * F_B_STRIDE + tx * 4]);
                float a4[4] = { av.x, av.y, av.z, av.w };
                float b4[4] = { bv.x, bv.y, bv.z, bv.w };
#pragma unroll
                for (int i = 0; i < 4; ++i)
#pragma unroll
                    for (int j = 0; j < 4; ++j)
                        acc[i][j] = __builtin_fmaf(a4[i], b4[j], acc[i][j]);
            }
        }

        {
            const float* cnp = (const float*)&cn;
            float Arow[4];
#pragma unroll
            for (int i = 0; i < 4; ++i) Arow[i] = As[ty * 4 + i];
#pragma unroll
            for (int j = 0; j < 4; ++j) {
                int kidx = k0 + tx * 4 + j;
                float kn = cnp[j];
#pragma unroll
                for (int i = 0; i < 4; ++i) {
                    float t1 = Arow[i] - 2.0f * acc[i][j];
                    float s  = t1 + kn;
                    if (s < bestv[i]) { bestv[i] = s; besti[i] = kidx; }
                }
            }
        }
    }

#pragma unroll
    for (int i = 0; i < 4; ++i) {
        float v = bestv[i]; int idx = besti[i];
#pragma unroll
        for (int off = 1; off < 16; off <<= 1) {
            float ov = __shfl_xor(v, off);
            int   oi = __shfl_xor(idx, off);
            if (ov < v || (ov == v && oi < idx)) { v = ov; idx = oi; }
        }
        if (tx == 0) bidx[ty * 4 + i] = idx;
    }
    __syncthreads();

    if (tid < TM) out[IDX_OFF + (size_t)blockIdx.x * TM + tid] = (float)bidx[tid];

    float lsum = 0.f;
    {
        int tt = tid & 31;
        int cq = tid >> 5;
        int myidx = bidx[tt];
        const float* myrow = cb + (size_t)myidx * DIM;
        float* oq = out + ((size_t)b * DIM) * NT + t0 + tt;
#pragma unroll 4
        for (int cc = 0; cc < 64; ++cc) {
            int c = cc * 4 + cq;
            float q = myrow[c];
            float d = q - Alds[c * F_A_STRIDE + tt];
            lsum += d * d;
            oq[(size_t)c * NT] = q;
        }
    }
#pragma unroll
    for (int off = 32; off > 0; off >>= 1) lsum += __shfl_down(lsum, off);
    if ((tid & 63) == 0) wred[tid >> 6] = lsum;
    __syncthreads();
    if (tid == 0) atomicAdd(loss_acc, (double)wred[0] + (double)wred[1]);
}

// ---------------- finalize scalar loss --------------------------------------
__global__ void k_final(const double* __restrict__ loss_acc, float* __restrict__ out) {
    out[LOSS_OFF] = (float)(*loss_acc * (1.25 / (double)Q_SIZE));
}

extern "C" void kernel_launch(void* const* d_in, const int* in_sizes, int n_in,
                              void* d_out, int out_size, void* d_ws, size_t ws_size,
                              hipStream_t stream) {
    const float* x  = (const float*)d_in[0];
    const float* cb = (const float*)d_in[1];
    float* out = (float*)d_out;
    double* loss_acc = (double*)d_ws;

    if (ws_size >= (size_t)WS_REQ) {
        float*    e2  = (float*)((char*)d_ws + WS_E2);
        ushort_t* cbf = (ushort_t*)((char*)d_ws + WS_CBF);
        hipLaunchKernelGGL(k_prep, dim3(133), dim3(256), 0, stream, cb, e2, cbf, loss_acc);
        hipLaunchKernelGGL(k_main_mfma, dim3(NROWS / TM), dim3(256), 0, stream,
                           x, cb, e2, cbf, out, loss_acc);
    } else {
        float* e2 = (float*)((char*)d_ws + 16);
        hipLaunchKernelGGL(k_norms_fb, dim3(K_CODES / 128), dim3(128), 0, stream,
                           cb, e2, loss_acc);
        hipLaunchKernelGGL(k_main_fp32, dim3(NROWS / TM), dim3(128), 0, stream,
                           x, cb, e2, out, loss_acc);
    }
    hipLaunchKernelGGL(k_final, dim3(1), dim3(1), 0, stream, loss_acc, out);
}